// Round 7
// baseline (1419.536 us; speedup 1.0000x reference)
//
#include <hip/hip_runtime.h>

typedef unsigned short ushort_t;
typedef __attribute__((ext_vector_type(4))) float f32x4;
typedef __attribute__((ext_vector_type(8))) short short8;

__device__ __forceinline__ ushort_t f2bf(float f) {
  union { float f; unsigned u; } v; v.f = f;
  unsigned r = v.u + 0x7fffu + ((v.u >> 16) & 1u);
  return (ushort_t)(r >> 16);
}
__device__ __forceinline__ unsigned pack2(float lo, float hi) {
  return (unsigned)f2bf(lo) | ((unsigned)f2bf(hi) << 16);
}

// ---------------- kernel 0a: weights fp32 -> bf16 (wq,wk,wv,wo concatenated) ----
__global__ __launch_bounds__(256) void cvt_w_k(const float* __restrict__ wq,
                                               const float* __restrict__ wk,
                                               const float* __restrict__ wv,
                                               const float* __restrict__ wo,
                                               ushort_t* __restrict__ dst) {
  int idx = (blockIdx.x * 256 + threadIdx.x) * 4;  // 0 .. 1048572
  int m = idx >> 18;
  int off = idx & 0x3ffff;
  const float* s = (m == 0) ? wq : (m == 1) ? wk : (m == 2) ? wv : wo;
  float4 v = *(const float4*)(s + off);
  ushort4 o;
  o.x = f2bf(v.x); o.y = f2bf(v.y); o.z = f2bf(v.z); o.w = f2bf(v.w);
  *(ushort4*)(dst + idx) = o;
}

// ---------------- kernel 0b: x (b,c,192,192) fp32 -> xT[token][c] bf16 ----------
__global__ __launch_bounds__(256) void xpose_k(const float* __restrict__ x,
                                               ushort_t* __restrict__ xT) {
  __shared__ ushort_t tile[128 * 80];  // [c_local][token], padded to 80
  int bid = blockIdx.x;                // 2304 windows * 4 c-chunks
  int win = bid >> 2, kc = bid & 3;
  int b = win / 576, rem = win % 576, wh = rem / 24, ww = rem % 24;
  int tid = threadIdx.x;
  {
    int c_l = tid >> 1, half = tid & 1;
    const float* xb = x + ((((size_t)b * 512 + kc * 128 + c_l) * 192 + wh * 8) * 192 + ww * 8);
#pragma unroll
    for (int ii = 0; ii < 4; ++ii) {
      int i = half * 4 + ii;
      float4 v0 = *(const float4*)(xb + i * 192);
      float4 v1 = *(const float4*)(xb + i * 192 + 4);
      uint4 u;
      u.x = (unsigned)f2bf(v0.x) | ((unsigned)f2bf(v0.y) << 16);
      u.y = (unsigned)f2bf(v0.z) | ((unsigned)f2bf(v0.w) << 16);
      u.z = (unsigned)f2bf(v1.x) | ((unsigned)f2bf(v1.y) << 16);
      u.w = (unsigned)f2bf(v1.z) | ((unsigned)f2bf(v1.w) << 16);
      *(uint4*)&tile[c_l * 80 + i * 8] = u;
    }
  }
  __syncthreads();
  {
    int tok = tid >> 2, q = tid & 3;
    unsigned w[16];
#pragma unroll
    for (int k = 0; k < 16; ++k) {
      unsigned lo = tile[(q * 32 + 2 * k) * 80 + tok];
      unsigned hi = tile[(q * 32 + 2 * k + 1) * 80 + tok];
      w[k] = lo | (hi << 16);
    }
    ushort_t* d = xT + ((size_t)(win * 64 + tok) * 512 + kc * 128 + q * 32);
#pragma unroll
    for (int s2 = 0; s2 < 4; ++s2) {
      uint4 u; u.x = w[s2 * 4 + 0]; u.y = w[s2 * 4 + 1]; u.z = w[s2 * 4 + 2]; u.w = w[s2 * 4 + 3];
      *(uint4*)(d + s2 * 8) = u;
    }
  }
}

// ---------------- kernel 1: per-window fused QKV + 8-head attention -------------
// Grid 2304, block 512 (8 waves), 1 block/CU. Wave w computes HEAD w's full
// q,k,v (64 outcols x 64 tokens, K=512) in ONE barrier-free run: 768 MFMA with
// 48 independent acc chains; weight loads pipeline under MFMA via ILP.
// Then acc packs to bf16 in-register (frees ~96 VGPR) and 4 attention rounds
// (2 heads each) run through shared LDS buffers.
__global__ __launch_bounds__(512, 2) void qkv_attn2_k(const ushort_t* __restrict__ xT,
                                                      const ushort_t* __restrict__ wB,
                                                      const float* __restrict__ beta,
                                                      ushort_t* __restrict__ O) {
  __shared__ ushort_t xws[64 * 520];   // [token][512c], pad->520
  __shared__ ushort_t qs[2][64 * 72];  // per-head q token-major [n][d]; reused as P
  __shared__ ushort_t ks[2][64 * 72];  // per-head k token-major [m][d]
  __shared__ ushort_t vs[2][64 * 72];  // per-head v d-major [d][m]
  int win = blockIdx.x;
  int t0 = win * 64;
  int tid = threadIdx.x, lane = tid & 63, wid = tid >> 6;  // wid 0..7 = head
  int l15 = lane & 15, l4 = lane >> 4;

  // ---- stage full window xT (64 tok x 512 ch bf16) into LDS, once ----
  {
    int token = tid >> 3, cb = (tid & 7) * 64;
    const uint4* src = (const uint4*)(xT + (size_t)(t0 + token) * 512 + cb);
    uint4* dst = (uint4*)&xws[token * 520 + cb];
#pragma unroll
    for (int s2 = 0; s2 < 8; ++s2) dst[s2] = src[s2];
  }
  __syncthreads();

  const f32x4 z = {0.f, 0.f, 0.f, 0.f};

  // ---- QKV for head wid: acc[ot][nt], ot = 16-col tile of head, nt = token tile
  f32x4 aq[4][4], ak[4][4], av[4][4];
#pragma unroll
  for (int i = 0; i < 4; ++i)
#pragma unroll
    for (int j = 0; j < 4; ++j) { aq[i][j] = z; ak[i][j] = z; av[i][j] = z; }

  const ushort_t* wbase = wB + (size_t)(wid * 64 + l15) * 512 + l4 * 8;

#pragma unroll
  for (int kk = 0; kk < 16; ++kk) {
    short8 a[4];
#pragma unroll
    for (int nt = 0; nt < 4; ++nt)
      a[nt] = *(const short8*)&xws[(nt * 16 + l15) * 520 + kk * 32 + l4 * 8];
    short8 bq[4], bk[4], bv[4];
#pragma unroll
    for (int ot = 0; ot < 4; ++ot) {
      const ushort_t* wp = wbase + ot * 8192 + kk * 32;
      bq[ot] = *(const short8*)(wp);
      bk[ot] = *(const short8*)(wp + 262144);
      bv[ot] = *(const short8*)(wp + 524288);
    }
#pragma unroll
    for (int ot = 0; ot < 4; ++ot)
#pragma unroll
      for (int nt = 0; nt < 4; ++nt) {
        aq[ot][nt] = __builtin_amdgcn_mfma_f32_16x16x32_bf16(a[nt], bq[ot], aq[ot][nt], 0, 0, 0);
        ak[ot][nt] = __builtin_amdgcn_mfma_f32_16x16x32_bf16(a[nt], bk[ot], ak[ot][nt], 0, 0, 0);
        av[ot][nt] = __builtin_amdgcn_mfma_f32_16x16x32_bf16(a[nt], bv[ot], av[ot][nt], 0, 0, 0);
      }
  }

  // ---- pack acc to bf16 in-register (halves live regs before attention) ----
  unsigned qp[4][4][2], kp[4][4][2], vp[4][4][2];
#pragma unroll
  for (int ot = 0; ot < 4; ++ot)
#pragma unroll
    for (int nt = 0; nt < 4; ++nt) {
      qp[ot][nt][0] = pack2(aq[ot][nt][0], aq[ot][nt][1]);
      qp[ot][nt][1] = pack2(aq[ot][nt][2], aq[ot][nt][3]);
      kp[ot][nt][0] = pack2(ak[ot][nt][0], ak[ot][nt][1]);
      kp[ot][nt][1] = pack2(ak[ot][nt][2], ak[ot][nt][3]);
      vp[ot][nt][0] = pack2(av[ot][nt][0], av[ot][nt][1]);
      vp[ot][nt][1] = pack2(av[ot][nt][2], av[ot][nt][3]);
    }

  // ---- 4 attention rounds: heads (2r, 2r+1) ----
#pragma unroll
  for (int r4 = 0; r4 < 4; ++r4) {
    if ((wid >> 1) == r4) {
      int hw = wid & 1;
#pragma unroll
      for (int ot = 0; ot < 4; ++ot) {
        int dd = ot * 16 + l15;
#pragma unroll
        for (int nt = 0; nt < 4; ++nt) {
#pragma unroll
          for (int pp = 0; pp < 2; ++pp) {
            int n = nt * 16 + l4 * 4 + pp * 2;
            qs[hw][n * 72 + dd]       = (ushort_t)(qp[ot][nt][pp] & 0xffffu);
            qs[hw][(n + 1) * 72 + dd] = (ushort_t)(qp[ot][nt][pp] >> 16);
            ks[hw][n * 72 + dd]       = (ushort_t)(kp[ot][nt][pp] & 0xffffu);
            ks[hw][(n + 1) * 72 + dd] = (ushort_t)(kp[ot][nt][pp] >> 16);
          }
          uint2 u; u.x = vp[ot][nt][0]; u.y = vp[ot][nt][1];
          *(uint2*)&vs[hw][dd * 72 + nt * 16 + l4 * 4] = u;
        }
      }
    }
    __syncthreads();

    int hh = wid >> 2, rowg = wid & 3;
    int h = r4 * 2 + hh;
    f32x4 sA[4];
#pragma unroll
    for (int i = 0; i < 4; ++i) sA[i] = z;
#pragma unroll
    for (int kk = 0; kk < 2; ++kk) {
      short8 aF = *(const short8*)&qs[hh][(rowg * 16 + l15) * 72 + kk * 32 + l4 * 8];
#pragma unroll
      for (int mt = 0; mt < 4; ++mt) {
        short8 bF = *(const short8*)&ks[hh][(mt * 16 + l15) * 72 + kk * 32 + l4 * 8];
        sA[mt] = __builtin_amdgcn_mfma_f32_16x16x32_bf16(aF, bF, sA[mt], 0, 0, 0);
      }
    }
    const float* betah = beta + h * 4096;
    float p[4][4];
    float rmax[4] = {-1e30f, -1e30f, -1e30f, -1e30f};
#pragma unroll
    for (int mt = 0; mt < 4; ++mt)
#pragma unroll
      for (int r = 0; r < 4; ++r) {
        int n = rowg * 16 + l4 * 4 + r;
        float val = sA[mt][r] * 0.125f + betah[n * 64 + mt * 16 + l15];
        p[mt][r] = val;
        rmax[r] = fmaxf(rmax[r], val);
      }
#pragma unroll
    for (int m = 1; m <= 8; m <<= 1)
#pragma unroll
      for (int r = 0; r < 4; ++r) rmax[r] = fmaxf(rmax[r], __shfl_xor(rmax[r], m, 64));
    float rsum[4] = {0.f, 0.f, 0.f, 0.f};
#pragma unroll
    for (int mt = 0; mt < 4; ++mt)
#pragma unroll
      for (int r = 0; r < 4; ++r) {
        p[mt][r] = __expf(p[mt][r] - rmax[r]);
        rsum[r] += p[mt][r];
      }
#pragma unroll
    for (int m = 1; m <= 8; m <<= 1)
#pragma unroll
      for (int r = 0; r < 4; ++r) rsum[r] += __shfl_xor(rsum[r], m, 64);
    float rinv[4];
#pragma unroll
    for (int r = 0; r < 4; ++r) rinv[r] = 1.f / rsum[r];
    // P overwrites this wave's own 16 rows of qs[hh]; only reader is this wave's
    // PV (same-wave DS ordering) -> no barrier needed here.
#pragma unroll
    for (int mt = 0; mt < 4; ++mt)
#pragma unroll
      for (int r = 0; r < 4; ++r)
        qs[hh][(rowg * 16 + l4 * 4 + r) * 72 + mt * 16 + l15] = f2bf(p[mt][r] * rinv[r]);

    f32x4 oA[4];
#pragma unroll
    for (int i = 0; i < 4; ++i) oA[i] = z;
#pragma unroll
    for (int kk = 0; kk < 2; ++kk) {
      short8 aF = *(const short8*)&qs[hh][(rowg * 16 + l15) * 72 + kk * 32 + l4 * 8];
#pragma unroll
      for (int dt = 0; dt < 4; ++dt) {
        short8 bF = *(const short8*)&vs[hh][(dt * 16 + l15) * 72 + kk * 32 + l4 * 8];
        oA[dt] = __builtin_amdgcn_mfma_f32_16x16x32_bf16(aF, bF, oA[dt], 0, 0, 0);
      }
    }
#pragma unroll
    for (int dt = 0; dt < 4; ++dt)
#pragma unroll
      for (int r = 0; r < 4; ++r) {
        int n = rowg * 16 + l4 * 4 + r;
        O[(size_t)(t0 + n) * 512 + h * 64 + dt * 16 + l15] = f2bf(oA[dt][r]);
      }
    __syncthreads();  // before next round's writers overwrite qs/ks/vs
  }
}

// ---------------- kernel 3: proj GEMM 64x256 tiles; full-line fp32 stores -------
__global__ __launch_bounds__(256) void proj_k3(const ushort_t* __restrict__ O,
                                               const ushort_t* __restrict__ woB,
                                               const float* __restrict__ bo,
                                               float* __restrict__ out) {
  __shared__ __align__(16) char smem_raw[64 * 72 * 2 + 256 * 72 * 2];  // 46080 B
  ushort_t* As = (ushort_t*)smem_raw;            // [64][72]
  ushort_t* Bs = (ushort_t*)smem_raw + 64 * 72;  // [256][72]
  float* Ct = (float*)smem_raw;                  // [64][132] epilogue (33792 B)
  int bid = blockIdx.x;
  int cwg = gridDim.x >> 3;
  int wg = (bid & 7) * cwg + (bid >> 3);
  int nn = wg >> 3, mm = wg & 7;                 // consecutive wg share B-tile
  int tid = threadIdx.x, lane = tid & 63, wid = tid >> 6;  // wid = window-in-tile
  int l15 = lane & 15, l4 = lane >> 4;
  const ushort_t* Asrc = woB + (size_t)(mm * 64) * 512;
  const ushort_t* Bsrc = O + (size_t)(nn * 256) * 512;

  const f32x4 z = {0.f, 0.f, 0.f, 0.f};
  f32x4 acc[4][4];
#pragma unroll
  for (int i = 0; i < 4; ++i)
#pragma unroll
    for (int j = 0; j < 4; ++j) acc[i][j] = z;

  int arow[2], aslot[2];
#pragma unroll
  for (int c = 0; c < 2; ++c) { int u = c * 256 + tid; arow[c] = u >> 3; aslot[c] = u & 7; }
  int brow[8], bslot[8];
#pragma unroll
  for (int c = 0; c < 8; ++c) { int u = c * 256 + tid; brow[c] = u >> 3; bslot[c] = u & 7; }

  for (int ks = 0; ks < 8; ++ks) {
    int ko = ks * 64;
    uint4 ta[2], tb[8];
#pragma unroll
    for (int c = 0; c < 2; ++c)
      ta[c] = *(const uint4*)&Asrc[(size_t)arow[c] * 512 + ko + aslot[c] * 8];
#pragma unroll
    for (int c = 0; c < 8; ++c)
      tb[c] = *(const uint4*)&Bsrc[(size_t)brow[c] * 512 + ko + bslot[c] * 8];
    __syncthreads();
#pragma unroll
    for (int c = 0; c < 2; ++c) *(uint4*)&As[arow[c] * 72 + aslot[c] * 8] = ta[c];
#pragma unroll
    for (int c = 0; c < 8; ++c) *(uint4*)&Bs[brow[c] * 72 + bslot[c] * 8] = tb[c];
    __syncthreads();
#pragma unroll
    for (int kk = 0; kk < 2; ++kk) {
      short8 aF[4], bF[4];
#pragma unroll
      for (int mi = 0; mi < 4; ++mi)
        aF[mi] = *(const short8*)&As[(mi * 16 + l15) * 72 + kk * 32 + l4 * 8];
#pragma unroll
      for (int ni = 0; ni < 4; ++ni)
        bF[ni] = *(const short8*)&Bs[(wid * 64 + ni * 16 + l15) * 72 + kk * 32 + l4 * 8];
#pragma unroll
      for (int mi = 0; mi < 4; ++mi)
#pragma unroll
        for (int ni = 0; ni < 4; ++ni)
          acc[mi][ni] = __builtin_amdgcn_mfma_f32_16x16x32_bf16(aF[mi], bF[ni], acc[mi][ni], 0, 0, 0);
    }
  }
  // ---- epilogue: 2 passes over i-halves; LDS [o][ (i&3)*32 + w*8 + j ] fp32 ----
#pragma unroll
  for (int p = 0; p < 2; ++p) {
    __syncthreads();
#pragma unroll
    for (int mi = 0; mi < 4; ++mi)
#pragma unroll
      for (int nq = 0; nq < 2; ++nq)
#pragma unroll
        for (int rr = 0; rr < 4; ++rr) {
          int o = mi * 16 + l4 * 4 + rr;
          int i3 = nq * 2 + (l15 >> 3);
          int col = i3 * 32 + wid * 8 + (l15 & 7);
          Ct[o * 132 + col] = acc[mi][p * 2 + nq][rr];
        }
    __syncthreads();
#pragma unroll
    for (int it = 0; it < 8; ++it) {
      int cidx = it * 256 + tid;
      int o_l = cidx >> 5, c4 = cidx & 31;
      float4 v = *(const float4*)&Ct[o_l * 132 + c4 * 4];
      int o = mm * 64 + o_l;
      float bias = bo[o];
      int w = (c4 & 7) >> 1, j = (c4 & 1) * 4, i = p * 4 + (c4 >> 3);
      int win = nn * 4 + w;
      int b = win / 576, rem = win % 576, wh = rem / 24, ww = rem % 24;
      size_t addr = (((size_t)b * 512 + o) * 192 + wh * 8 + i) * 192 + ww * 8 + j;
      float4 r;
      r.x = v.x + bias; r.y = v.y + bias; r.z = v.z + bias; r.w = v.w + bias;
      *(float4*)&out[addr] = r;
    }
  }
}

extern "C" void kernel_launch(void* const* d_in, const int* in_sizes, int n_in,
                              void* d_out, int out_size, void* d_ws, size_t ws_size,
                              hipStream_t stream) {
  const float* x    = (const float*)d_in[0];
  const float* wq   = (const float*)d_in[1];
  const float* wk   = (const float*)d_in[2];
  const float* wv   = (const float*)d_in[3];
  const float* wo   = (const float*)d_in[4];
  const float* bo   = (const float*)d_in[5];
  const float* beta = (const float*)d_in[6];

  // layout in d_ws (ws >= 578 MiB confirmed): wB 2 MiB | xT 151 MB | O 151 MB
  ushort_t* wB = (ushort_t*)d_ws;
  ushort_t* xT = (ushort_t*)((char*)d_ws + (size_t)2097152);
  ushort_t* O  = (ushort_t*)((char*)d_ws + (size_t)2097152 + (size_t)147456 * 1024);

  cvt_w_k<<<1024, 256, 0, stream>>>(wq, wk, wv, wo, wB);
  xpose_k<<<2304 * 4, 256, 0, stream>>>(x, xT);
  qkv_attn2_k<<<2304, 512, 0, stream>>>(xT, wB, beta, O);
  proj_k3<<<(147456 / 256) * 8, 256, 0, stream>>>(O, wB + 3 * 262144, bo, (float*)d_out);
}

// Round 8
// 1160.061 us; speedup vs baseline: 1.2237x; 1.2237x over previous
//
#include <hip/hip_runtime.h>

typedef unsigned short ushort_t;
typedef __attribute__((ext_vector_type(4))) float f32x4;
typedef __attribute__((ext_vector_type(8))) short short8;

__device__ __forceinline__ ushort_t f2bf(float f) {
  union { float f; unsigned u; } v; v.f = f;
  unsigned r = v.u + 0x7fffu + ((v.u >> 16) & 1u);
  return (ushort_t)(r >> 16);
}
__device__ __forceinline__ unsigned pack2(float lo, float hi) {
  return (unsigned)f2bf(lo) | ((unsigned)f2bf(hi) << 16);
}

// ---------------- kernel 0a: weights fp32 -> bf16 (wq,wk,wv,wo concatenated) ----
__global__ __launch_bounds__(256) void cvt_w_k(const float* __restrict__ wq,
                                               const float* __restrict__ wk,
                                               const float* __restrict__ wv,
                                               const float* __restrict__ wo,
                                               ushort_t* __restrict__ dst) {
  int idx = (blockIdx.x * 256 + threadIdx.x) * 4;  // 0 .. 1048572
  int m = idx >> 18;
  int off = idx & 0x3ffff;
  const float* s = (m == 0) ? wq : (m == 1) ? wk : (m == 2) ? wv : wo;
  float4 v = *(const float4*)(s + off);
  ushort4 o;
  o.x = f2bf(v.x); o.y = f2bf(v.y); o.z = f2bf(v.z); o.w = f2bf(v.w);
  *(ushort4*)(dst + idx) = o;
}

// ---------------- kernel 0b: x (b,c,192,192) fp32 -> xT[token][c] bf16 ----------
__global__ __launch_bounds__(256) void xpose_k(const float* __restrict__ x,
                                               ushort_t* __restrict__ xT) {
  __shared__ ushort_t tile[128 * 80];  // [c_local][token], padded to 80
  int bid = blockIdx.x;                // 2304 windows * 4 c-chunks
  int win = bid >> 2, kc = bid & 3;
  int b = win / 576, rem = win % 576, wh = rem / 24, ww = rem % 24;
  int tid = threadIdx.x;
  {
    int c_l = tid >> 1, half = tid & 1;
    const float* xb = x + ((((size_t)b * 512 + kc * 128 + c_l) * 192 + wh * 8) * 192 + ww * 8);
#pragma unroll
    for (int ii = 0; ii < 4; ++ii) {
      int i = half * 4 + ii;
      float4 v0 = *(const float4*)(xb + i * 192);
      float4 v1 = *(const float4*)(xb + i * 192 + 4);
      uint4 u;
      u.x = (unsigned)f2bf(v0.x) | ((unsigned)f2bf(v0.y) << 16);
      u.y = (unsigned)f2bf(v0.z) | ((unsigned)f2bf(v0.w) << 16);
      u.z = (unsigned)f2bf(v1.x) | ((unsigned)f2bf(v1.y) << 16);
      u.w = (unsigned)f2bf(v1.z) | ((unsigned)f2bf(v1.w) << 16);
      *(uint4*)&tile[c_l * 80 + i * 8] = u;
    }
  }
  __syncthreads();
  {
    int tok = tid >> 2, q = tid & 3;
    unsigned w[16];
#pragma unroll
    for (int k = 0; k < 16; ++k) {
      unsigned lo = tile[(q * 32 + 2 * k) * 80 + tok];
      unsigned hi = tile[(q * 32 + 2 * k + 1) * 80 + tok];
      w[k] = lo | (hi << 16);
    }
    ushort_t* d = xT + ((size_t)(win * 64 + tok) * 512 + kc * 128 + q * 32);
#pragma unroll
    for (int s2 = 0; s2 < 4; ++s2) {
      uint4 u; u.x = w[s2 * 4 + 0]; u.y = w[s2 * 4 + 1]; u.z = w[s2 * 4 + 2]; u.w = w[s2 * 4 + 3];
      *(uint4*)(d + s2 * 8) = u;
    }
  }
}

// ---------------- kernel 1: fused QKV + attention, 70 KB LDS -> 2 blocks/CU -----
// Grid 2304, block 512 (8 waves). Per head-pair: K staged in 128-chunks, double
// buffered (T14 issue-early/write-late). vs aliases xstage (idle during attn).
__global__ __launch_bounds__(512, 4) void qkv_attn3_k(const ushort_t* __restrict__ xT,
                                                      const ushort_t* __restrict__ wB,
                                                      const float* __restrict__ beta,
                                                      ushort_t* __restrict__ O) {
  // 71680 B total: xstage[2][64][136] | qs[2][64*72] | ks[2][64*72]; vs aliases xstage
  __shared__ __align__(16) ushort_t smem[2 * 8704 + 2 * 4608 + 2 * 4608];
  ushort_t* xstage = smem;            // [2][64][136]
  ushort_t* qs = smem + 17408;        // [2][64*72]  (also reused as P)
  ushort_t* ks = smem + 26624;        // [2][64*72]
  ushort_t* vs = smem;                // [2][64*72]  alias of xstage

  int win = blockIdx.x;
  int t0 = win * 64;
  int tid = threadIdx.x, lane = tid & 63, wid = tid >> 6;  // wid 0..7
  int l15 = lane & 15, l4 = lane >> 4;

  // staging map: two 16B units per thread; u = c*512+tid -> row=u>>4, slot=u&15
  int srow[2], sslot[2];
#pragma unroll
  for (int c = 0; c < 2; ++c) { int u = c * 512 + tid; srow[c] = u >> 4; sslot[c] = u & 15; }

  const f32x4 z = {0.f, 0.f, 0.f, 0.f};

  for (int hcc = 0; hcc < 4; ++hcc) {
    f32x4 aq[4], ak[4], av[4];
#pragma unroll
    for (int i = 0; i < 4; ++i) { aq[i] = z; ak[i] = z; av[i] = z; }
    int ocol = hcc * 128 + wid * 16 + l15;
    const ushort_t* wqr = wB + (size_t)ocol * 512 + l4 * 8;
    const ushort_t* wkr = wqr + 262144;
    const ushort_t* wvr = wqr + 524288;

    // prologue: stage K-chunk 0 into buf 0
#pragma unroll
    for (int c = 0; c < 2; ++c) {
      uint4 v = *(const uint4*)&xT[(size_t)(t0 + srow[c]) * 512 + sslot[c] * 8];
      *(uint4*)&xstage[srow[c] * 136 + sslot[c] * 8] = v;
    }
    __syncthreads();

#pragma unroll
    for (int kb = 0; kb < 4; ++kb) {
      uint4 nx[2];
      if (kb < 3) {  // issue next chunk's loads early; land after compute
#pragma unroll
        for (int c = 0; c < 2; ++c)
          nx[c] = *(const uint4*)&xT[(size_t)(t0 + srow[c]) * 512 + (kb + 1) * 128 + sslot[c] * 8];
      }
      const ushort_t* xb = xstage + (kb & 1) * 8704;
      __builtin_amdgcn_s_setprio(1);
#pragma unroll
      for (int kkL = 0; kkL < 4; ++kkL) {
        int kk = kb * 4 + kkL;
        short8 bq = *(const short8*)(wqr + kk * 32);
        short8 bk = *(const short8*)(wkr + kk * 32);
        short8 bv = *(const short8*)(wvr + kk * 32);
#pragma unroll
        for (int nt = 0; nt < 4; ++nt) {
          short8 a = *(const short8*)&xb[(nt * 16 + l15) * 136 + kkL * 32 + l4 * 8];
          aq[nt] = __builtin_amdgcn_mfma_f32_16x16x32_bf16(a, bq, aq[nt], 0, 0, 0);
          ak[nt] = __builtin_amdgcn_mfma_f32_16x16x32_bf16(a, bk, ak[nt], 0, 0, 0);
          av[nt] = __builtin_amdgcn_mfma_f32_16x16x32_bf16(a, bv, av[nt], 0, 0, 0);
        }
      }
      __builtin_amdgcn_s_setprio(0);
      if (kb < 3) {
#pragma unroll
        for (int c = 0; c < 2; ++c)
          *(uint4*)&xstage[((kb + 1) & 1) * 8704 + srow[c] * 136 + sslot[c] * 8] = nx[c];
        __syncthreads();
      }
    }
    __syncthreads();  // all QKV xstage reads done (vs aliases xstage region)

    // ---- write q,k (token-major) and v (d-major) to LDS ----
    int hw = wid >> 2;
    int dd = (wid * 16 + l15) & 63;
#pragma unroll
    for (int nt = 0; nt < 4; ++nt) {
#pragma unroll
      for (int r = 0; r < 4; ++r) {
        int n = nt * 16 + l4 * 4 + r;
        qs[hw * 4608 + n * 72 + dd] = f2bf(aq[nt][r]);
        ks[hw * 4608 + n * 72 + dd] = f2bf(ak[nt][r]);
      }
      uint2 u;
      u.x = pack2(av[nt][0], av[nt][1]);
      u.y = pack2(av[nt][2], av[nt][3]);
      *(uint2*)&vs[hw * 4608 + dd * 72 + nt * 16 + l4 * 4] = u;
    }
    __syncthreads();

    // ---- attention: wave -> head hh = wid>>2, rows rowg*16.. ----
    int hh = wid >> 2, rowg = wid & 3;
    int h = hcc * 2 + hh;
    f32x4 sA[4];
#pragma unroll
    for (int i = 0; i < 4; ++i) sA[i] = z;
#pragma unroll
    for (int kk = 0; kk < 2; ++kk) {
      short8 aF = *(const short8*)&qs[hh * 4608 + (rowg * 16 + l15) * 72 + kk * 32 + l4 * 8];
#pragma unroll
      for (int mt = 0; mt < 4; ++mt) {
        short8 bF = *(const short8*)&ks[hh * 4608 + (mt * 16 + l15) * 72 + kk * 32 + l4 * 8];
        sA[mt] = __builtin_amdgcn_mfma_f32_16x16x32_bf16(aF, bF, sA[mt], 0, 0, 0);
      }
    }
    const float* betah = beta + h * 4096;
    float p[4][4];
    float rmax[4] = {-1e30f, -1e30f, -1e30f, -1e30f};
#pragma unroll
    for (int mt = 0; mt < 4; ++mt)
#pragma unroll
      for (int r = 0; r < 4; ++r) {
        int n = rowg * 16 + l4 * 4 + r;
        float val = sA[mt][r] * 0.125f + betah[n * 64 + mt * 16 + l15];
        p[mt][r] = val;
        rmax[r] = fmaxf(rmax[r], val);
      }
#pragma unroll
    for (int m = 1; m <= 8; m <<= 1)
#pragma unroll
      for (int r = 0; r < 4; ++r) rmax[r] = fmaxf(rmax[r], __shfl_xor(rmax[r], m, 64));
    float rsum[4] = {0.f, 0.f, 0.f, 0.f};
#pragma unroll
    for (int mt = 0; mt < 4; ++mt)
#pragma unroll
      for (int r = 0; r < 4; ++r) {
        p[mt][r] = __expf(p[mt][r] - rmax[r]);
        rsum[r] += p[mt][r];
      }
#pragma unroll
    for (int m = 1; m <= 8; m <<= 1)
#pragma unroll
      for (int r = 0; r < 4; ++r) rsum[r] += __shfl_xor(rsum[r], m, 64);
    float rinv[4];
#pragma unroll
    for (int r = 0; r < 4; ++r) rinv[r] = 1.f / rsum[r];
    // P overwrites this wave's own 16 rows of qs[hh]; only reader is this wave's
    // PV (same-wave DS ordering) -> no barrier needed here.
#pragma unroll
    for (int mt = 0; mt < 4; ++mt)
#pragma unroll
      for (int r = 0; r < 4; ++r)
        qs[hh * 4608 + (rowg * 16 + l4 * 4 + r) * 72 + mt * 16 + l15] = f2bf(p[mt][r] * rinv[r]);

    f32x4 oA[4];
#pragma unroll
    for (int i = 0; i < 4; ++i) oA[i] = z;
#pragma unroll
    for (int kk = 0; kk < 2; ++kk) {
      short8 aF = *(const short8*)&qs[hh * 4608 + (rowg * 16 + l15) * 72 + kk * 32 + l4 * 8];
#pragma unroll
      for (int dt = 0; dt < 4; ++dt) {
        short8 bF = *(const short8*)&vs[hh * 4608 + (dt * 16 + l15) * 72 + kk * 32 + l4 * 8];
        oA[dt] = __builtin_amdgcn_mfma_f32_16x16x32_bf16(aF, bF, oA[dt], 0, 0, 0);
      }
    }
#pragma unroll
    for (int dt = 0; dt < 4; ++dt)
#pragma unroll
      for (int r = 0; r < 4; ++r) {
        int n = rowg * 16 + l4 * 4 + r;
        O[(size_t)(t0 + n) * 512 + h * 64 + dt * 16 + l15] = f2bf(oA[dt][r]);
      }
    __syncthreads();  // before next head pair's staging overwrites xstage/vs
  }
}

// ---------------- kernel 3: proj GEMM 64x256 tiles; full-line fp32 stores -------
__global__ __launch_bounds__(256) void proj_k3(const ushort_t* __restrict__ O,
                                               const ushort_t* __restrict__ woB,
                                               const float* __restrict__ bo,
                                               float* __restrict__ out) {
  __shared__ __align__(16) char smem_raw[64 * 72 * 2 + 256 * 72 * 2];  // 46080 B
  ushort_t* As = (ushort_t*)smem_raw;            // [64][72]
  ushort_t* Bs = (ushort_t*)smem_raw + 64 * 72;  // [256][72]
  float* Ct = (float*)smem_raw;                  // [64][132] epilogue (33792 B)
  int bid = blockIdx.x;
  int cwg = gridDim.x >> 3;
  int wg = (bid & 7) * cwg + (bid >> 3);
  int nn = wg >> 3, mm = wg & 7;                 // consecutive wg share B-tile
  int tid = threadIdx.x, lane = tid & 63, wid = tid >> 6;  // wid = window-in-tile
  int l15 = lane & 15, l4 = lane >> 4;
  const ushort_t* Asrc = woB + (size_t)(mm * 64) * 512;
  const ushort_t* Bsrc = O + (size_t)(nn * 256) * 512;

  const f32x4 z = {0.f, 0.f, 0.f, 0.f};
  f32x4 acc[4][4];
#pragma unroll
  for (int i = 0; i < 4; ++i)
#pragma unroll
    for (int j = 0; j < 4; ++j) acc[i][j] = z;

  int arow[2], aslot[2];
#pragma unroll
  for (int c = 0; c < 2; ++c) { int u = c * 256 + tid; arow[c] = u >> 3; aslot[c] = u & 7; }
  int brow[8], bslot[8];
#pragma unroll
  for (int c = 0; c < 8; ++c) { int u = c * 256 + tid; brow[c] = u >> 3; bslot[c] = u & 7; }

  for (int ks = 0; ks < 8; ++ks) {
    int ko = ks * 64;
    uint4 ta[2], tb[8];
#pragma unroll
    for (int c = 0; c < 2; ++c)
      ta[c] = *(const uint4*)&Asrc[(size_t)arow[c] * 512 + ko + aslot[c] * 8];
#pragma unroll
    for (int c = 0; c < 8; ++c)
      tb[c] = *(const uint4*)&Bsrc[(size_t)brow[c] * 512 + ko + bslot[c] * 8];
    __syncthreads();
#pragma unroll
    for (int c = 0; c < 2; ++c) *(uint4*)&As[arow[c] * 72 + aslot[c] * 8] = ta[c];
#pragma unroll
    for (int c = 0; c < 8; ++c) *(uint4*)&Bs[brow[c] * 72 + bslot[c] * 8] = tb[c];
    __syncthreads();
#pragma unroll
    for (int kk = 0; kk < 2; ++kk) {
      short8 aF[4], bF[4];
#pragma unroll
      for (int mi = 0; mi < 4; ++mi)
        aF[mi] = *(const short8*)&As[(mi * 16 + l15) * 72 + kk * 32 + l4 * 8];
#pragma unroll
      for (int ni = 0; ni < 4; ++ni)
        bF[ni] = *(const short8*)&Bs[(wid * 64 + ni * 16 + l15) * 72 + kk * 32 + l4 * 8];
#pragma unroll
      for (int mi = 0; mi < 4; ++mi)
#pragma unroll
        for (int ni = 0; ni < 4; ++ni)
          acc[mi][ni] = __builtin_amdgcn_mfma_f32_16x16x32_bf16(aF[mi], bF[ni], acc[mi][ni], 0, 0, 0);
    }
  }
  // ---- epilogue: 2 passes over i-halves; LDS [o][ (i&3)*32 + w*8 + j ] fp32 ----
#pragma unroll
  for (int p = 0; p < 2; ++p) {
    __syncthreads();
#pragma unroll
    for (int mi = 0; mi < 4; ++mi)
#pragma unroll
      for (int nq = 0; nq < 2; ++nq)
#pragma unroll
        for (int rr = 0; rr < 4; ++rr) {
          int o = mi * 16 + l4 * 4 + rr;
          int i3 = nq * 2 + (l15 >> 3);
          int col = i3 * 32 + wid * 8 + (l15 & 7);
          Ct[o * 132 + col] = acc[mi][p * 2 + nq][rr];
        }
    __syncthreads();
#pragma unroll
    for (int it = 0; it < 8; ++it) {
      int cidx = it * 256 + tid;
      int o_l = cidx >> 5, c4 = cidx & 31;
      float4 v = *(const float4*)&Ct[o_l * 132 + c4 * 4];
      int o = mm * 64 + o_l;
      float bias = bo[o];
      int w = (c4 & 7) >> 1, j = (c4 & 1) * 4, i = p * 4 + (c4 >> 3);
      int win = nn * 4 + w;
      int b = win / 576, rem = win % 576, wh = rem / 24, ww = rem % 24;
      size_t addr = (((size_t)b * 512 + o) * 192 + wh * 8 + i) * 192 + ww * 8 + j;
      float4 r;
      r.x = v.x + bias; r.y = v.y + bias; r.z = v.z + bias; r.w = v.w + bias;
      *(float4*)&out[addr] = r;
    }
  }
}

extern "C" void kernel_launch(void* const* d_in, const int* in_sizes, int n_in,
                              void* d_out, int out_size, void* d_ws, size_t ws_size,
                              hipStream_t stream) {
  const float* x    = (const float*)d_in[0];
  const float* wq   = (const float*)d_in[1];
  const float* wk   = (const float*)d_in[2];
  const float* wv   = (const float*)d_in[3];
  const float* wo   = (const float*)d_in[4];
  const float* bo   = (const float*)d_in[5];
  const float* beta = (const float*)d_in[6];

  // layout in d_ws (ws >= 578 MiB confirmed): wB 2 MiB | xT 151 MB | O 151 MB
  ushort_t* wB = (ushort_t*)d_ws;
  ushort_t* xT = (ushort_t*)((char*)d_ws + (size_t)2097152);
  ushort_t* O  = (ushort_t*)((char*)d_ws + (size_t)2097152 + (size_t)147456 * 1024);

  cvt_w_k<<<1024, 256, 0, stream>>>(wq, wk, wv, wo, wB);
  xpose_k<<<2304 * 4, 256, 0, stream>>>(x, xT);
  qkv_attn3_k<<<2304, 512, 0, stream>>>(xT, wB, beta, O);
  proj_k3<<<(147456 / 256) * 8, 256, 0, stream>>>(O, wB + 3 * 262144, bo, (float*)d_out);
}

// Round 9
// 857.582 us; speedup vs baseline: 1.6553x; 1.3527x over previous
//
#include <hip/hip_runtime.h>

typedef unsigned short ushort_t;
typedef __attribute__((ext_vector_type(4))) float f32x4;
typedef __attribute__((ext_vector_type(8))) short short8;

__device__ __forceinline__ ushort_t f2bf(float f) {
  union { float f; unsigned u; } v; v.f = f;
  unsigned r = v.u + 0x7fffu + ((v.u >> 16) & 1u);
  return (ushort_t)(r >> 16);
}
__device__ __forceinline__ unsigned pack2(float lo, float hi) {
  return (unsigned)f2bf(lo) | ((unsigned)f2bf(hi) << 16);
}

// ---------------- kernel 0a: weights fp32 -> bf16 (wq,wk,wv,wo concatenated) ----
__global__ __launch_bounds__(256) void cvt_w_k(const float* __restrict__ wq,
                                               const float* __restrict__ wk,
                                               const float* __restrict__ wv,
                                               const float* __restrict__ wo,
                                               ushort_t* __restrict__ dst) {
  int idx = (blockIdx.x * 256 + threadIdx.x) * 4;  // 0 .. 1048572
  int m = idx >> 18;
  int off = idx & 0x3ffff;
  const float* s = (m == 0) ? wq : (m == 1) ? wk : (m == 2) ? wv : wo;
  float4 v = *(const float4*)(s + off);
  ushort4 o;
  o.x = f2bf(v.x); o.y = f2bf(v.y); o.z = f2bf(v.z); o.w = f2bf(v.w);
  *(ushort4*)(dst + idx) = o;
}

// ---------------- kernel 1: fused QKV + 8-head attention, staged direct from x --
// Grid 2304 (XCD-chunk-swizzled), block 512 (8 waves), 1 block/CU (122 KB LDS).
// Staging: in-block transpose x(c,i,j) -> xws[tok][c], bank-balanced via XOR of
// the 16B c-unit with i (= tok>>3). MFMA A-reads apply the same XOR per lane.
__global__ __launch_bounds__(512, 1) void qkv_attn4_k(const float* __restrict__ x,
                                                      const ushort_t* __restrict__ wB,
                                                      const float* __restrict__ beta,
                                                      ushort_t* __restrict__ O) {
  __shared__ ushort_t xws[64 * 520];   // [token][512c swizzled], pad->520
  __shared__ ushort_t qs[2][64 * 72];  // per-head q token-major [n][d]; reused as P
  __shared__ ushort_t ks[2][64 * 72];  // per-head k token-major [m][d]
  __shared__ ushort_t vs[2][64 * 72];  // per-head v d-major [d][m]
  int bid = blockIdx.x;
  int win = (bid & 7) * 288 + (bid >> 3);   // ww-neighbors share an XCD
  int b = win / 576, rem = win % 576, wh = rem / 24, ww = rem % 24;
  int t0 = win * 64;
  int tid = threadIdx.x, lane = tid & 63, wid = tid >> 6;  // wid 0..7
  int l15 = lane & 15, l4 = lane >> 4;

  // ---- stage window direct from x, once: unit u = c*8+i; 8 units/thread ----
#pragma unroll
  for (int k = 0; k < 8; ++k) {
    int u = tid + k * 512;
    int c = u >> 3, i = u & 7;
    const float* p = x + (((size_t)b * 512 + c) * 192 + wh * 8 + i) * 192 + ww * 8;
    float4 v0 = *(const float4*)p;
    float4 v1 = *(const float4*)(p + 4);
    int colb = (((c >> 3) ^ i) << 3) + (c & 7);
    ushort_t* dst = &xws[(i * 8) * 520 + colb];
    dst[0 * 520] = f2bf(v0.x);
    dst[1 * 520] = f2bf(v0.y);
    dst[2 * 520] = f2bf(v0.z);
    dst[3 * 520] = f2bf(v0.w);
    dst[4 * 520] = f2bf(v1.x);
    dst[5 * 520] = f2bf(v1.y);
    dst[6 * 520] = f2bf(v1.z);
    dst[7 * 520] = f2bf(v1.w);
  }
  __syncthreads();

  const f32x4 z = {0.f, 0.f, 0.f, 0.f};
  int rowb[4], ii[4];
#pragma unroll
  for (int nt = 0; nt < 4; ++nt) {
    rowb[nt] = (nt * 16 + l15) * 520;
    ii[nt] = nt * 2 + (l15 >> 3);       // tok>>3 for this fragment row
  }

  for (int hcc = 0; hcc < 4; ++hcc) {
    // ---- QKV for head pair hcc (out-cols [hcc*128, hcc*128+128)) ----
    f32x4 aq[4], ak[4], av[4];
#pragma unroll
    for (int i = 0; i < 4; ++i) { aq[i] = z; ak[i] = z; av[i] = z; }
    int ocol = hcc * 128 + wid * 16 + l15;
    const ushort_t* wqr = wB + (size_t)ocol * 512 + l4 * 8;
    const ushort_t* wkr = wqr + 262144;
    const ushort_t* wvr = wqr + 524288;
#pragma unroll
    for (int kk = 0; kk < 16; ++kk) {
      short8 bq = *(const short8*)(wqr + kk * 32);
      short8 bk = *(const short8*)(wkr + kk * 32);
      short8 bv = *(const short8*)(wvr + kk * 32);
      int cu = kk * 4 + l4;
#pragma unroll
      for (int nt = 0; nt < 4; ++nt) {
        short8 a = *(const short8*)&xws[rowb[nt] + ((cu ^ ii[nt]) << 3)];
        aq[nt] = __builtin_amdgcn_mfma_f32_16x16x32_bf16(a, bq, aq[nt], 0, 0, 0);
        ak[nt] = __builtin_amdgcn_mfma_f32_16x16x32_bf16(a, bk, ak[nt], 0, 0, 0);
        av[nt] = __builtin_amdgcn_mfma_f32_16x16x32_bf16(a, bv, av[nt], 0, 0, 0);
      }
    }
    int hw = wid >> 2;            // which head of the pair this wave's cols fall in
    int dd = (wid * 16 + l15) & 63;
#pragma unroll
    for (int nt = 0; nt < 4; ++nt) {
#pragma unroll
      for (int r = 0; r < 4; ++r) {
        int n = nt * 16 + l4 * 4 + r;
        qs[hw][n * 72 + dd] = f2bf(aq[nt][r]);
        ks[hw][n * 72 + dd] = f2bf(ak[nt][r]);
      }
      uint2 u;
      u.x = pack2(av[nt][0], av[nt][1]);
      u.y = pack2(av[nt][2], av[nt][3]);
      *(uint2*)&vs[hw][dd * 72 + nt * 16 + l4 * 4] = u;
    }
    __syncthreads();

    // ---- attention: wave handles head h = hcc*2 + (wid>>2), rows rowg*16.. ----
    int hh = wid >> 2, rowg = wid & 3;
    int h = hcc * 2 + hh;
    f32x4 sA[4];
#pragma unroll
    for (int i = 0; i < 4; ++i) sA[i] = z;
#pragma unroll
    for (int kk = 0; kk < 2; ++kk) {
      short8 aF = *(const short8*)&qs[hh][(rowg * 16 + l15) * 72 + kk * 32 + l4 * 8];
#pragma unroll
      for (int mt = 0; mt < 4; ++mt) {
        short8 bF = *(const short8*)&ks[hh][(mt * 16 + l15) * 72 + kk * 32 + l4 * 8];
        sA[mt] = __builtin_amdgcn_mfma_f32_16x16x32_bf16(aF, bF, sA[mt], 0, 0, 0);
      }
    }
    const float* betah = beta + h * 4096;
    float p[4][4];
    float rmax[4] = {-1e30f, -1e30f, -1e30f, -1e30f};
#pragma unroll
    for (int mt = 0; mt < 4; ++mt)
#pragma unroll
      for (int r = 0; r < 4; ++r) {
        int n = rowg * 16 + l4 * 4 + r;
        float val = sA[mt][r] * 0.125f + betah[n * 64 + mt * 16 + l15];
        p[mt][r] = val;
        rmax[r] = fmaxf(rmax[r], val);
      }
#pragma unroll
    for (int m = 1; m <= 8; m <<= 1)
#pragma unroll
      for (int r = 0; r < 4; ++r) rmax[r] = fmaxf(rmax[r], __shfl_xor(rmax[r], m, 64));
    float rsum[4] = {0.f, 0.f, 0.f, 0.f};
#pragma unroll
    for (int mt = 0; mt < 4; ++mt)
#pragma unroll
      for (int r = 0; r < 4; ++r) {
        p[mt][r] = __expf(p[mt][r] - rmax[r]);
        rsum[r] += p[mt][r];
      }
#pragma unroll
    for (int m = 1; m <= 8; m <<= 1)
#pragma unroll
      for (int r = 0; r < 4; ++r) rsum[r] += __shfl_xor(rsum[r], m, 64);
    float rinv[4];
#pragma unroll
    for (int r = 0; r < 4; ++r) rinv[r] = 1.f / rsum[r];
    // P overwrites this wave's own 16 rows of qs[hh]; only reader is this wave's
    // PV (same-wave DS ordering) -> no barrier needed here.
#pragma unroll
    for (int mt = 0; mt < 4; ++mt)
#pragma unroll
      for (int r = 0; r < 4; ++r)
        qs[hh][(rowg * 16 + l4 * 4 + r) * 72 + mt * 16 + l15] = f2bf(p[mt][r] * rinv[r]);

    f32x4 oA[4];
#pragma unroll
    for (int i = 0; i < 4; ++i) oA[i] = z;
#pragma unroll
    for (int kk = 0; kk < 2; ++kk) {
      short8 aF = *(const short8*)&qs[hh][(rowg * 16 + l15) * 72 + kk * 32 + l4 * 8];
#pragma unroll
      for (int dt = 0; dt < 4; ++dt) {
        short8 bF = *(const short8*)&vs[hh][(dt * 16 + l15) * 72 + kk * 32 + l4 * 8];
        oA[dt] = __builtin_amdgcn_mfma_f32_16x16x32_bf16(aF, bF, oA[dt], 0, 0, 0);
      }
    }
#pragma unroll
    for (int dt = 0; dt < 4; ++dt)
#pragma unroll
      for (int r = 0; r < 4; ++r) {
        int n = rowg * 16 + l4 * 4 + r;
        O[(size_t)(t0 + n) * 512 + h * 64 + dt * 16 + l15] = f2bf(oA[dt][r]);
      }
    __syncthreads();  // before next head pair overwrites qs/ks/vs
  }
}

// ---------------- kernel 2: proj GEMM (R2 structure, empirically fastest) -------
// Grid 2304*2 (XCD-chunk-swizzled); win half-tiles; scalar fp32 scatter stores.
__global__ __launch_bounds__(256) void proj_kb(const ushort_t* __restrict__ O,
                                               const ushort_t* __restrict__ woB,
                                               const float* __restrict__ bo,
                                               float* __restrict__ out) {
  __shared__ ushort_t ows[64 * 136];
  int bid = blockIdx.x;
  int wg = (bid & 7) * 576 + (bid >> 3);   // 4608 = 8*576; neighbors share XCD
  int win = wg >> 1, mo = (wg & 1) * 256;
  int b = win / 576, rem = win % 576, wh = rem / 24, ww = rem % 24;
  int tid = threadIdx.x, lane = tid & 63, wid = tid >> 6;
  int l15 = lane & 15, l4 = lane >> 4;
  int t0 = win * 64;
  f32x4 z = {0.f, 0.f, 0.f, 0.f};
  f32x4 acc[4][4];
#pragma unroll
  for (int i = 0; i < 4; ++i)
#pragma unroll
    for (int j = 0; j < 4; ++j) acc[i][j] = z;
  int stok = tid >> 2, sq = tid & 3;
  for (int kcc = 0; kcc < 4; ++kcc) {
    {
      const uint4* src = (const uint4*)(O + ((size_t)(t0 + stok) * 512 + kcc * 128 + sq * 32));
      uint4* dstv = (uint4*)&ows[stok * 136 + sq * 32];
#pragma unroll
      for (int s2 = 0; s2 < 4; ++s2) dstv[s2] = src[s2];
    }
    __syncthreads();
#pragma unroll
    for (int kk = 0; kk < 4; ++kk) {
      short8 bF[4];
#pragma unroll
      for (int nt = 0; nt < 4; ++nt)
        bF[nt] = *(const short8*)&ows[(nt * 16 + l15) * 136 + kk * 32 + l4 * 8];
      int cg = kcc * 128 + kk * 32 + l4 * 8;
#pragma unroll
      for (int mt = 0; mt < 4; ++mt) {
        int orow = mo + wid * 64 + mt * 16 + l15;
        short8 aF = *(const short8*)(woB + (size_t)orow * 512 + cg);
#pragma unroll
        for (int nt = 0; nt < 4; ++nt)
          acc[mt][nt] = __builtin_amdgcn_mfma_f32_16x16x32_bf16(aF, bF[nt], acc[mt][nt], 0, 0, 0);
      }
    }
    __syncthreads();
  }
#pragma unroll
  for (int mt = 0; mt < 4; ++mt) {
#pragma unroll
    for (int r = 0; r < 4; ++r) {
      int o = mo + wid * 64 + mt * 16 + l4 * 4 + r;
      float bias = bo[o];
#pragma unroll
      for (int nt = 0; nt < 4; ++nt) {
        int tok = nt * 16 + l15;
        int i = tok >> 3, j = tok & 7;
        out[(((size_t)b * 512 + o) * 192 + wh * 8 + i) * 192 + ww * 8 + j] = acc[mt][nt][r] + bias;
      }
    }
  }
}

extern "C" void kernel_launch(void* const* d_in, const int* in_sizes, int n_in,
                              void* d_out, int out_size, void* d_ws, size_t ws_size,
                              hipStream_t stream) {
  const float* x    = (const float*)d_in[0];
  const float* wq   = (const float*)d_in[1];
  const float* wk   = (const float*)d_in[2];
  const float* wv   = (const float*)d_in[3];
  const float* wo   = (const float*)d_in[4];
  const float* bo   = (const float*)d_in[5];
  const float* beta = (const float*)d_in[6];

  // d_ws layout: wB 2 MiB | O 151 MB   (xT / xpose eliminated)
  ushort_t* wB = (ushort_t*)d_ws;
  ushort_t* O  = (ushort_t*)((char*)d_ws + (size_t)2097152);

  cvt_w_k<<<1024, 256, 0, stream>>>(wq, wk, wv, wo, wB);
  qkv_attn4_k<<<2304, 512, 0, stream>>>(x, wB, beta, O);
  proj_kb<<<4608, 256, 0, stream>>>(O, wB + 3 * 262144, bo, (float*)d_out);
}